// Round 2
// baseline (2370.221 us; speedup 1.0000x reference)
//
#include <hip/hip_runtime.h>
#include <math.h>

// ---------------------------------------------------------------------------
// ConvCaps fused pipeline, fp32 baseline. (Resubmission — round 0/1 benches
// died with UnresponsiveContainer before execution; source desk-checked.)
//
// Shapes: b=8, x=(8,544,64,64); B=32 capsules x PSIZE=16 pose + 32 act ch.
// oh=ow=32 (k=3, stride=2, pad=1). hw=1024, kk=9.
//
// Stage 1 (stats):  per (b,cb) mean/var over im2col'ed pose data, computed
//                   directly on x with multiplicity weights m(i) in {1,2}.
// Stage 2 (prep):   softmaxes + fold gamma/gsm/w_sm into W2eff[32][32];
//                   fold BN params into scale/bias.
// Stage 3 (G):      per input pixel: normalize, scramble (ps*32+cb = cb'*16+ps'),
//                   scale by act*(folded gamma), apply W2eff -> G[pix][512].
// Stage 4 (conv1):  im2col GEMM (K=4608) + BN + sigmoid -> Aact[8192][288].
// Stage 5 (conv2):  im2col GEMM (K=4608) + Aact GEMM (K=288) + BN + relu
//                   -> out (8,544,32,32).
// ---------------------------------------------------------------------------

#define LN_EPS 1e-8f

// ws layout (float offsets)
static const size_t O_MU   = 0;                   // 256
static const size_t O_RSTD = 256;                 // 256
static const size_t O_W2   = 512;                 // 1024
static const size_t O_BN1S = 1536;                // 288
static const size_t O_BN1B = 1824;                // 288
static const size_t O_BN2S = 2112;                // 544
static const size_t O_BN2B = 2656;                // 544
static const size_t O_G    = 4096;                // 8*64*64*512 = 16777216
static const size_t O_ACT  = 4096 + 16777216;     // 8192*288    = 2359296

// ---------------------------------------------------------------------------
__global__ __launch_bounds__(256) void prep_kernel(
    const float* __restrict__ wts,   // (32,33)
    const float* __restrict__ gamma, // (32)
    const float* __restrict__ bn1s, const float* __restrict__ bn1bi,
    const float* __restrict__ bn1m, const float* __restrict__ bn1v,
    const float* __restrict__ bn2s, const float* __restrict__ bn2bi,
    const float* __restrict__ bn2m, const float* __restrict__ bn2v,
    float* __restrict__ ws)
{
  __shared__ float wsm[32 * 33];
  __shared__ float gs[32];
  int t = threadIdx.x;
  if (t < 33) {
    float mx = -1e30f;
    for (int c = 0; c < 32; ++c) mx = fmaxf(mx, wts[c * 33 + t]);
    float sum = 0.f;
    for (int c = 0; c < 32; ++c) {
      float e = expf(wts[c * 33 + t] - mx);
      wsm[c * 33 + t] = e;
      sum += e;
    }
    float inv = 1.f / sum;
    for (int c = 0; c < 32; ++c) wsm[c * 33 + t] *= inv;
  }
  if (t == 64) {  // gamma softmax (serial; trivial size)
    float mx = -1e30f;
    for (int d = 0; d < 32; ++d) mx = fmaxf(mx, gamma[d]);
    float sum = 0.f;
    for (int d = 0; d < 32; ++d) { float e = expf(gamma[d] - mx); gs[d] = e; sum += e; }
    float inv = 1.f / sum;
    for (int d = 0; d < 32; ++d) gs[d] *= inv;
  }
  __syncthreads();
  for (int i = t; i < 1024; i += 256) {
    int c = i >> 5, d = i & 31;
    ws[O_W2 + i] = (wsm[c * 33 + d] + wsm[c * 33 + 32] * gs[d]) * gamma[d];
  }
  for (int i = t; i < 288; i += 256) {
    float s = bn1s[i] / sqrtf(bn1v[i] + 1e-5f);
    ws[O_BN1S + i] = s;
    ws[O_BN1B + i] = bn1bi[i] - bn1m[i] * s;
  }
  for (int i = t; i < 544; i += 256) {
    float s = bn2s[i] / sqrtf(bn2v[i] + 1e-5f);
    ws[O_BN2S + i] = s;
    ws[O_BN2B + i] = bn2bi[i] - bn2m[i] * s;
  }
}

// ---------------------------------------------------------------------------
// Stats: one block per (b, cb). Weighted sums over 16 pose channels x 64x64.
// Multiplicity m(i) = 2 if (i odd && i != 63) else 1; pad rows/cols are zero.
__global__ __launch_bounds__(256) void stats_kernel(
    const float* __restrict__ x, float* __restrict__ ws)
{
  int g = blockIdx.x;             // b*32 + cb
  int b = g >> 5, cb = g & 31;
  const float* base = x + (((size_t)(b * 544 + cb * 16)) << 12);
  float s = 0.f, q = 0.f;
  for (int idx = threadIdx.x; idx < 65536; idx += 256) {
    int p = idx & 4095;
    int hi = p >> 6, wi = p & 63;
    float wh = ((hi & 1) && hi != 63) ? 2.f : 1.f;
    float ww = ((wi & 1) && wi != 63) ? 2.f : 1.f;
    float v = base[idx];          // idx = ch*4096 + p exactly (ch stride 4096)
    float wgt = wh * ww;
    s += wgt * v;
    q += wgt * v * v;
  }
  __shared__ float sb[256], qb[256];
  int t = threadIdx.x;
  sb[t] = s; qb[t] = q;
  __syncthreads();
  for (int off = 128; off > 0; off >>= 1) {
    if (t < off) { sb[t] += sb[t + off]; qb[t] += qb[t + off]; }
    __syncthreads();
  }
  if (t == 0) {
    const float N = 147456.f;     // hw*kk*PSIZE, including padded zeros
    float mean = sb[0] / N;
    float var = (qb[0] - sb[0] * sb[0] / N) / (N - 1.f);  // ddof=1
    ws[O_MU + g] = mean;
    ws[O_RSTD + g] = 1.f / sqrtf(var + LN_EPS);
  }
}

// ---------------------------------------------------------------------------
// G: per input pixel, 512-vector = W2eff @ (act * scrambled-normalized pose).
// Grid: b(8) x hi(64) x wquarter(4) = 2048 blocks; 16 pixels per block.
__global__ __launch_bounds__(256) void g_kernel(
    const float* __restrict__ x, float* __restrict__ ws)
{
  __shared__ __align__(16) float raw[16][545];   // [pix][ch], pad row->545
  __shared__ __align__(16) float ut[16][576];    // [pix][ps'*36 + d']
  __shared__ float w2s[1024];
  __shared__ float mus[32], rss[32];
  int t = threadIdx.x;
  int pb = blockIdx.x;
  int b = pb >> 8, hi = (pb >> 2) & 63, wi0 = (pb & 3) << 4;

  {  // load 16 pixels x 544 channels, coalesced (16 wi x 16 ch per iter)
    int ch0 = t >> 4, wl = t & 15;
    size_t gbase = ((size_t)b * 544) << 12;
    size_t rowoff = ((size_t)hi << 6) + (size_t)(wi0 + wl);
    for (int it = 0; it < 34; ++it) {
      int ch = it * 16 + ch0;
      raw[wl][ch] = x[gbase + ((size_t)ch << 12) + rowoff];
    }
  }
  for (int i = t; i < 1024; i += 256) w2s[i] = ws[O_W2 + i];
  if (t < 32) { mus[t] = ws[O_MU + b * 32 + t]; rss[t] = ws[O_RSTD + b * 32 + t]; }
  __syncthreads();

  {  // u[d'][ps'] = act[d'] * (raw[src(j)] - mu[cb])*rstd[cb], j = d'*16+ps'
    int dl = t & 15, psp = t >> 4;
    for (int it = 0; it < 32; ++it) {
      int pix = it >> 1, half = it & 1;
      int dp = half * 16 + dl;            // d' in [0,32)
      int j = (dp << 4) + psp;            // j in [0,512)
      int cbv = j & 31, psv = j >> 5;     // scramble inverse: ps*32+cb = j
      float val = (raw[pix][(cbv << 4) + psv] - mus[cbv]) * rss[cbv];
      ut[pix][psp * 36 + dp] = raw[pix][512 + dp] * val;
    }
  }
  __syncthreads();

  {  // G[c*16+ps'] = sum_d W2eff[c][d] * u[d][ps'] ; 2 c-values per thread
    int c0 = t >> 4, psp = t & 15;
    float w2a[32], w2b[32];
#pragma unroll
    for (int d = 0; d < 32; ++d) {
      w2a[d] = w2s[c0 * 32 + d];
      w2b[d] = w2s[(c0 + 16) * 32 + d];
    }
    float* Gp = ws + O_G + ((size_t)((((b << 6) + hi) << 6) + wi0)) * 512;
    for (int pix = 0; pix < 16; ++pix) {
      float acc0 = 0.f, acc1 = 0.f;
      const float* up = &ut[pix][psp * 36];
#pragma unroll
      for (int k = 0; k < 8; ++k) {
        float4 u4 = *reinterpret_cast<const float4*>(up + 4 * k);
        acc0 = fmaf(w2a[4 * k + 0], u4.x, acc0);
        acc0 = fmaf(w2a[4 * k + 1], u4.y, acc0);
        acc0 = fmaf(w2a[4 * k + 2], u4.z, acc0);
        acc0 = fmaf(w2a[4 * k + 3], u4.w, acc0);
        acc1 = fmaf(w2b[4 * k + 0], u4.x, acc1);
        acc1 = fmaf(w2b[4 * k + 1], u4.y, acc1);
        acc1 = fmaf(w2b[4 * k + 2], u4.z, acc1);
        acc1 = fmaf(w2b[4 * k + 3], u4.w, acc1);
      }
      float* gp = Gp + (size_t)pix * 512;
      gp[t] = acc0;              // (c0)*16+psp == t
      gp[256 + t] = acc1;        // (c0+16)*16+psp == 256+t
    }
  }
}

// ---------------------------------------------------------------------------
// Conv GEMM: pos-tile 64, o-tile BO, K-chunk 32 staged in LDS.
// SECOND=0: conv1 (K=4608), epilogue BN+sigmoid -> Aact.
// SECOND=1: conv2 (K=4608 im2col + 288 act), epilogue BN+relu -> out (NCHW).
template <int BO, int NO, int KTOT, int SECOND>
__global__ __launch_bounds__(256) void conv_kernel(
    const float* __restrict__ G, const float* __restrict__ actIn,
    const float* __restrict__ Wm, const float* __restrict__ bns,
    const float* __restrict__ bnb, float* __restrict__ outp)
{
  __shared__ __align__(16) float At[64][36];
  __shared__ __align__(16) float Wt[BO][36];
  const int NTO = (SECOND ? 544 : 288) / BO;  // = 4
  int bt = blockIdx.x;
  int ot = bt % NTO, pt = bt / NTO;
  int p0 = pt << 6, o0 = ot * BO;
  int t = threadIdx.x;
  int tx = t & 7, ty = t >> 3;
  float acc0[NO], acc1[NO];
#pragma unroll
  for (int j = 0; j < NO; ++j) { acc0[j] = 0.f; acc1[j] = 0.f; }

  const int NCH = KTOT >> 5;
  for (int kc = 0; kc < NCH; ++kc) {
    int k0 = kc << 5;
    // stage A (64 pos x 32 k), im2col gather (or act rows for k>=4608)
#pragma unroll
    for (int s = 0; s < 2; ++s) {
      int slot = t + (s << 8);
      int r = slot >> 3, cc4 = (slot & 7) << 2;
      int pos = p0 + r;
      float4 v = make_float4(0.f, 0.f, 0.f, 0.f);
      if (SECOND && k0 >= 4608) {
        v = *reinterpret_cast<const float4*>(
            &actIn[(size_t)pos * 288 + (k0 - 4608) + cc4]);
      } else {
        int kpos = k0 >> 9;                 // 0..8
        int kh = kpos / 3, kw = kpos % 3;
        int bb = pos >> 10, h = (pos >> 5) & 31, w = pos & 31;
        int hi2 = 2 * h + kh - 1, wi2 = 2 * w + kw - 1;
        if ((unsigned)hi2 < 64u && (unsigned)wi2 < 64u)
          v = *reinterpret_cast<const float4*>(
              &G[(((size_t)((((bb << 6) + hi2) << 6) + wi2)) << 9) +
                 (k0 & 511) + cc4]);
      }
      *reinterpret_cast<float4*>(&At[r][cc4]) = v;
    }
    // stage W (BO x 32)
    for (int slot = t; slot < BO * 8; slot += 256) {
      int r = slot >> 3, cc4 = (slot & 7) << 2;
      *reinterpret_cast<float4*>(&Wt[r][cc4]) =
          *reinterpret_cast<const float4*>(
              &Wm[(size_t)(o0 + r) * KTOT + k0 + cc4]);
    }
    __syncthreads();
#pragma unroll
    for (int cs = 0; cs < 8; ++cs) {
      float4 a0 = *reinterpret_cast<const float4*>(&At[ty][cs << 2]);
      float4 a1 = *reinterpret_cast<const float4*>(&At[ty + 32][cs << 2]);
#pragma unroll
      for (int j = 0; j < NO; ++j) {
        float4 wv = *reinterpret_cast<const float4*>(&Wt[tx + (j << 3)][cs << 2]);
        acc0[j] = fmaf(a0.x, wv.x, acc0[j]);
        acc0[j] = fmaf(a0.y, wv.y, acc0[j]);
        acc0[j] = fmaf(a0.z, wv.z, acc0[j]);
        acc0[j] = fmaf(a0.w, wv.w, acc0[j]);
        acc1[j] = fmaf(a1.x, wv.x, acc1[j]);
        acc1[j] = fmaf(a1.y, wv.y, acc1[j]);
        acc1[j] = fmaf(a1.z, wv.z, acc1[j]);
        acc1[j] = fmaf(a1.w, wv.w, acc1[j]);
      }
    }
    __syncthreads();
  }
  // epilogue: BN fold + activation + store
#pragma unroll
  for (int j = 0; j < NO; ++j) {
    int o = o0 + tx + (j << 3);
    float sc = bns[o], bi = bnb[o];
    {
      int pos = p0 + ty;
      float z = fmaf(acc0[j], sc, bi);
      if (SECOND) {
        int bb = pos >> 10, hw_ = pos & 1023;
        outp[(((size_t)(bb * 544 + o)) << 10) + hw_] = fmaxf(z, 0.f);
      } else {
        outp[(size_t)pos * 288 + o] = 1.f / (1.f + expf(-z));
      }
    }
    {
      int pos = p0 + ty + 32;
      float z = fmaf(acc1[j], sc, bi);
      if (SECOND) {
        int bb = pos >> 10, hw_ = pos & 1023;
        outp[(((size_t)(bb * 544 + o)) << 10) + hw_] = fmaxf(z, 0.f);
      } else {
        outp[(size_t)pos * 288 + o] = 1.f / (1.f + expf(-z));
      }
    }
  }
}

// ---------------------------------------------------------------------------
extern "C" void kernel_launch(void* const* d_in, const int* in_sizes, int n_in,
                              void* d_out, int out_size, void* d_ws,
                              size_t ws_size, hipStream_t stream)
{
  const float* x       = (const float*)d_in[0];
  const float* wts     = (const float*)d_in[1];
  const float* gamma   = (const float*)d_in[2];
  const float* conv1_w = (const float*)d_in[3];
  const float* bn1s    = (const float*)d_in[4];
  const float* bn1b    = (const float*)d_in[5];
  const float* bn1m    = (const float*)d_in[6];
  const float* bn1v    = (const float*)d_in[7];
  const float* conv2_w = (const float*)d_in[8];
  const float* bn2s    = (const float*)d_in[9];
  const float* bn2b    = (const float*)d_in[10];
  const float* bn2m    = (const float*)d_in[11];
  const float* bn2v    = (const float*)d_in[12];
  float* ws = (float*)d_ws;
  float* out = (float*)d_out;

  prep_kernel<<<1, 256, 0, stream>>>(wts, gamma, bn1s, bn1b, bn1m, bn1v,
                                     bn2s, bn2b, bn2m, bn2v, ws);
  stats_kernel<<<256, 256, 0, stream>>>(x, ws);
  g_kernel<<<2048, 256, 0, stream>>>(x, ws);
  conv_kernel<72, 9, 4608, 0><<<512, 256, 0, stream>>>(
      ws + O_G, nullptr, conv1_w, ws + O_BN1S, ws + O_BN1B, ws + O_ACT);
  conv_kernel<136, 17, 4896, 1><<<512, 256, 0, stream>>>(
      ws + O_G, ws + O_ACT, conv2_w, ws + O_BN2S, ws + O_BN2B, out);
}

// Round 4
// 294.923 us; speedup vs baseline: 8.0367x; 8.0367x over previous
//
#include <hip/hip_runtime.h>
#include <math.h>

// ---------------------------------------------------------------------------
// ConvCaps fused pipeline, MFMA bf16 version. (Resubmission — R3 bench died
// with UnresponsiveContainer before execution; source desk-checked twice.)
//
// prep   : softmaxes + fold W2eff[32][32]; fold BN params; zerobuf.
// stats  : per (b,cb) weighted mean/var (im2col multiplicity); zero Aact pads.
// wcvt   : conv1_w/conv2_w fp32 -> bf16, fragment-linear layouts (swizzle baked).
// g      : per input pixel, G[pix][512] bf16 (normalize+scramble+act*gamma+W2eff).
// fused  : GEMM [8192 x 864 x 4608]: cols 0..287 -> BN1+sigmoid -> Aact bf16;
//          cols 288..831 -> partial f32 (conv2 G-part, pre-BN).
// act    : GEMM [8192 x 576 x 320] over Aact + partial -> BN2+relu -> out NCHW.
// ---------------------------------------------------------------------------

typedef unsigned short u16;
typedef __attribute__((ext_vector_type(8))) short short8;
typedef __attribute__((ext_vector_type(16))) float f32x16;

#define MFMA32(a, b, c) __builtin_amdgcn_mfma_f32_32x32x16_bf16(a, b, c, 0, 0, 0)

#define LN_EPS 1e-8f

// f32 region offsets (float index)
#define O_MU    0
#define O_RSTD  256
#define O_W2    512
#define O_BN1S  1536
#define O_BN1B  1824
#define O_BN2S  2112
#define O_BN2B  2656
#define O_ZB    3200     // 64 zero floats (OOB staging target)

// byte offsets of big regions
#define O_G_B     16384ull                       // u16[16777216]  (33.5 MB)
#define O_AACT_B  (O_G_B + 33554432ull)          // u16[8192*320]  (5.24 MB)
#define O_PART_B  (O_AACT_B + 5242880ull)        // f32[8192*544]  (17.8 MB)
#define O_WF_B    (O_PART_B + 17825792ull)       // u16[9*72*6144] (7.96 MB)
#define O_WA_B    (O_WF_B + 7962624ull)          // u16[6*5*6144]  (0.37 MB)

__device__ __forceinline__ u16 f2bf(float f) {
  union { float f; unsigned u; } v; v.f = f;
  unsigned r = (v.u + 0x7fffu + ((v.u >> 16) & 1u)) >> 16;
  return (u16)r;
}

__device__ __forceinline__ void gll16(const void* g, void* l) {
  __builtin_amdgcn_global_load_lds(
      (const __attribute__((address_space(1))) unsigned int*)g,
      (__attribute__((address_space(3))) unsigned int*)l, 16, 0, 0);
}

// ---------------------------------------------------------------------------
__global__ __launch_bounds__(256) void prep_kernel(
    const float* __restrict__ wts, const float* __restrict__ gamma,
    const float* __restrict__ bn1s, const float* __restrict__ bn1bi,
    const float* __restrict__ bn1m, const float* __restrict__ bn1v,
    const float* __restrict__ bn2s, const float* __restrict__ bn2bi,
    const float* __restrict__ bn2m, const float* __restrict__ bn2v,
    float* __restrict__ ws)
{
  __shared__ float wsm[32 * 33];
  __shared__ float gs[32];
  int t = threadIdx.x;
  if (t < 33) {
    float mx = -1e30f;
    for (int c = 0; c < 32; ++c) mx = fmaxf(mx, wts[c * 33 + t]);
    float sum = 0.f;
    for (int c = 0; c < 32; ++c) {
      float e = expf(wts[c * 33 + t] - mx);
      wsm[c * 33 + t] = e; sum += e;
    }
    float inv = 1.f / sum;
    for (int c = 0; c < 32; ++c) wsm[c * 33 + t] *= inv;
  }
  if (t == 64) {
    float mx = -1e30f;
    for (int d = 0; d < 32; ++d) mx = fmaxf(mx, gamma[d]);
    float sum = 0.f;
    for (int d = 0; d < 32; ++d) { float e = expf(gamma[d] - mx); gs[d] = e; sum += e; }
    float inv = 1.f / sum;
    for (int d = 0; d < 32; ++d) gs[d] *= inv;
  }
  __syncthreads();
  for (int i = t; i < 1024; i += 256) {
    int c = i >> 5, d = i & 31;
    ws[O_W2 + i] = (wsm[c * 33 + d] + wsm[c * 33 + 32] * gs[d]) * gamma[d];
  }
  for (int i = t; i < 288; i += 256) {
    float s = bn1s[i] / sqrtf(bn1v[i] + 1e-5f);
    ws[O_BN1S + i] = s;
    ws[O_BN1B + i] = bn1bi[i] - bn1m[i] * s;
  }
  for (int i = t; i < 544; i += 256) {
    float s = bn2s[i] / sqrtf(bn2v[i] + 1e-5f);
    ws[O_BN2S + i] = s;
    ws[O_BN2B + i] = bn2bi[i] - bn2m[i] * s;
  }
  if (t < 64) ws[O_ZB + t] = 0.f;
}

// ---------------------------------------------------------------------------
__global__ __launch_bounds__(256) void stats_kernel(
    const float* __restrict__ x, float* __restrict__ ws, u16* __restrict__ Aact)
{
  int g = blockIdx.x;
  int b = g >> 5, cb = g & 31;
  const float* base = x + (((size_t)(b * 544 + cb * 16)) << 12);
  float s = 0.f, q = 0.f;
  for (int idx = threadIdx.x; idx < 65536; idx += 256) {
    int p = idx & 4095;
    int hi = p >> 6, wi = p & 63;
    float wh = ((hi & 1) && hi != 63) ? 2.f : 1.f;
    float ww = ((wi & 1) && wi != 63) ? 2.f : 1.f;
    float v = base[idx];
    float wgt = wh * ww;
    s += wgt * v;
    q += wgt * v * v;
  }
  __shared__ float sb[256], qb[256];
  int t = threadIdx.x;
  sb[t] = s; qb[t] = q;
  __syncthreads();
  for (int off = 128; off > 0; off >>= 1) {
    if (t < off) { sb[t] += sb[t + off]; qb[t] += qb[t + off]; }
    __syncthreads();
  }
  if (t == 0) {
    const float N = 147456.f;
    float mean = sb[0] / N;
    float var = (qb[0] - sb[0] * sb[0] / N) / (N - 1.f);
    ws[O_MU + g] = mean;
    ws[O_RSTD + g] = 1.f / sqrtf(var + LN_EPS);
  }
  // zero Aact pad cols [288,320) for positions [g*32, g*32+32)
  for (int i = t; i < 1024; i += 256) {
    int pos = (g << 5) + (i >> 5);
    Aact[(size_t)pos * 320 + 288 + (i & 31)] = 0;
  }
}

// ---------------------------------------------------------------------------
// Weight conversion to fragment-linear bf16 (swizzle-free direct frag order).
// Wf slot layout: [ob(9)][ch(72)][nt(3)][ks(4)][lane(64)][8 elems]
// Wa slot layout: [ob(6)][ch(5)][nt(3)][ks(4)][lane(64)][8 elems]
__global__ __launch_bounds__(256) void wcvt_kernel(
    const float* __restrict__ w1, const float* __restrict__ w2,
    u16* __restrict__ Wf, u16* __restrict__ Wa)
{
  int sid = blockIdx.x * 256 + threadIdx.x;   // < 520704 exactly
  if (sid < 497664) {
    int cb = sid / 768, si = sid - cb * 768;
    int ob = cb / 72, ch = cb - ob * 72;
    int nt = si >> 8, ks = (si >> 6) & 3, l2 = si & 63;
    int o = ob * 96 + (nt << 5) + (l2 & 31);
    int kf = (ch << 6) + (ks << 4) + ((l2 >> 5) << 3);
    u16* dst = Wf + (size_t)sid * 8;
#pragma unroll
    for (int e = 0; e < 8; ++e) {
      int k = kf + e;
      float v = 0.f;
      if (o < 288) v = w1[(size_t)o * 4608 + k];
      else if (o < 832) v = w2[(size_t)(o - 288) * 4896 + k];
      dst[e] = f2bf(v);
    }
  } else {
    int s2 = sid - 497664;                    // < 23040
    int cb = s2 / 768, si = s2 - cb * 768;
    int ob = cb / 5, ch = cb - ob * 5;
    int nt = si >> 8, ks = (si >> 6) & 3, l2 = si & 63;
    int o = ob * 96 + (nt << 5) + (l2 & 31);
    int kf = (ch << 6) + (ks << 4) + ((l2 >> 5) << 3);
    u16* dst = Wa + (size_t)s2 * 8;
#pragma unroll
    for (int e = 0; e < 8; ++e) {
      int k = kf + e;
      float v = (o < 544 && k < 288) ? w2[(size_t)o * 4896 + 4608 + k] : 0.f;
      dst[e] = f2bf(v);
    }
  }
}

// ---------------------------------------------------------------------------
__global__ __launch_bounds__(256) void g_kernel(
    const float* __restrict__ x, const float* __restrict__ ws,
    u16* __restrict__ Gb)
{
  __shared__ __align__(16) float raw[16][545];
  __shared__ __align__(16) float ut[16][576];
  __shared__ float w2s[1024];
  __shared__ float mus[32], rss[32];
  int t = threadIdx.x;
  int pb = blockIdx.x;
  int b = pb >> 8, hi = (pb >> 2) & 63, wi0 = (pb & 3) << 4;

  {
    int ch0 = t >> 4, wl = t & 15;
    size_t gbase = ((size_t)b * 544) << 12;
    size_t rowoff = ((size_t)hi << 6) + (size_t)(wi0 + wl);
    for (int it = 0; it < 34; ++it) {
      int ch = it * 16 + ch0;
      raw[wl][ch] = x[gbase + ((size_t)ch << 12) + rowoff];
    }
  }
  for (int i = t; i < 1024; i += 256) w2s[i] = ws[O_W2 + i];
  if (t < 32) { mus[t] = ws[O_MU + b * 32 + t]; rss[t] = ws[O_RSTD + b * 32 + t]; }
  __syncthreads();

  {
    int dl = t & 15, psp = t >> 4;
    for (int it = 0; it < 32; ++it) {
      int pix = it >> 1, half = it & 1;
      int dp = half * 16 + dl;
      int j = (dp << 4) + psp;
      int cbv = j & 31, psv = j >> 5;
      float val = (raw[pix][(cbv << 4) + psv] - mus[cbv]) * rss[cbv];
      ut[pix][psp * 36 + dp] = raw[pix][512 + dp] * val;
    }
  }
  __syncthreads();

  {
    int c0 = t >> 4, psp = t & 15;
    float w2a[32], w2b[32];
#pragma unroll
    for (int d = 0; d < 32; ++d) {
      w2a[d] = w2s[c0 * 32 + d];
      w2b[d] = w2s[(c0 + 16) * 32 + d];
    }
    u16* Gp = Gb + ((size_t)((((b << 6) + hi) << 6) + wi0)) * 512;
    for (int pix = 0; pix < 16; ++pix) {
      float acc0 = 0.f, acc1 = 0.f;
      const float* up = &ut[pix][psp * 36];
#pragma unroll
      for (int k = 0; k < 8; ++k) {
        float4 u4 = *reinterpret_cast<const float4*>(up + 4 * k);
        acc0 = fmaf(w2a[4 * k + 0], u4.x, acc0);
        acc0 = fmaf(w2a[4 * k + 1], u4.y, acc0);
        acc0 = fmaf(w2a[4 * k + 2], u4.z, acc0);
        acc0 = fmaf(w2a[4 * k + 3], u4.w, acc0);
        acc1 = fmaf(w2b[4 * k + 0], u4.x, acc1);
        acc1 = fmaf(w2b[4 * k + 1], u4.y, acc1);
        acc1 = fmaf(w2b[4 * k + 2], u4.z, acc1);
        acc1 = fmaf(w2b[4 * k + 3], u4.w, acc1);
      }
      u16* gp = Gp + (size_t)pix * 512;
      gp[t] = f2bf(acc0);
      gp[256 + t] = f2bf(acc1);
    }
  }
}

// ---------------------------------------------------------------------------
// Fused GEMM: M=8192, N=864 (288 conv1 + 544 conv2-G + 32 pad), K=4608.
// BM=128, BN=96, 4 waves, wave tile 32x96, mfma 32x32x16.
__global__ __launch_bounds__(256) void gemm_fused(
    const u16* __restrict__ Gb, const u16* __restrict__ Wf,
    const float* __restrict__ wsf, u16* __restrict__ Aact,
    float* __restrict__ partial)
{
  __shared__ __align__(16) u16 Al[2][128 * 64];   // 32 KB
  const int t = threadIdx.x;
  const int wid = t >> 6, l = t & 63;
  int bx = blockIdx.x;
  // XCD-bijective swizzle: 576 = 8 xcd * 72; same-mt blocks co-located per XCD.
  int xcd = bx & 7, idx = bx >> 3;          // idx < 72
  int mt = xcd + ((idx & 7) << 3);          // 0..63
  int ob = idx >> 3;                        // 0..8
  int p0 = mt << 7;

  // staging per-lane precompute (4 issues of 8 rows per wave)
  int hb[4], wb[4], jsw[4], srow[4];
  size_t pb[4];
#pragma unroll
  for (int s = 0; s < 4; ++s) {
    int r = (wid << 5) + (s << 3) + (l >> 3);
    int pos = p0 + r;
    int b_ = pos >> 10, h_ = (pos >> 5) & 31, w_ = pos & 31;
    pb[s] = ((size_t)b_) << 12;
    hb[s] = 2 * h_ - 1;
    wb[s] = 2 * w_ - 1;
    jsw[s] = ((l & 7) ^ (r & 7)) << 3;       // swizzled element offset in row
    srow[s] = (wid << 5) + (s << 3);         // wave-uniform LDS row base
  }
  const u16* zb = (const u16*)(wsf + O_ZB);

  f32x16 acc0 = {}, acc1 = {}, acc2 = {};

  auto stage = [&](int ch, int buf) {
    int kpos = ch >> 3;
    int kh = kpos / 3, kw = kpos - kh * 3;
    int c0 = (ch & 7) << 6;
#pragma unroll
    for (int s = 0; s < 4; ++s) {
      int hi = hb[s] + kh, wi = wb[s] + kw;
      bool ok = ((unsigned)hi < 64u) && ((unsigned)wi < 64u);
      const u16* src = ok
          ? (Gb + ((pb[s] + ((size_t)hi << 6) + (size_t)wi) << 9) + c0 + jsw[s])
          : (zb + jsw[s]);
      gll16(src, &Al[buf][srow[s] << 6]);
    }
  };

  stage(0, 0);
  __syncthreads();

  int bufp = 0;
  const int rr = (wid << 5) + (l & 31);
  for (int ch = 0; ch < 72; ++ch) {
    // B fragments for this chunk (direct global, coalesced, L1/L2-resident)
    const u16* wbase = Wf + (((size_t)(ob * 72 + ch)) * 6144) + (l << 3);
    short8 bf0[4], bf1[4], bf2[4];
#pragma unroll
    for (int ks = 0; ks < 4; ++ks) {
      bf0[ks] = *(const short8*)(wbase + (ks << 9));
      bf1[ks] = *(const short8*)(wbase + ((4 + ks) << 9));
      bf2[ks] = *(const short8*)(wbase + ((8 + ks) << 9));
    }
    if (ch + 1 < 72) stage(ch + 1, bufp ^ 1);
#pragma unroll
    for (int ks = 0; ks < 4; ++ks) {
      int jl = (ks << 1) + (l >> 5);
      short8 av = *(const short8*)&Al[bufp][(rr << 6) + ((jl ^ (rr & 7)) << 3)];
      acc0 = MFMA32(av, bf0[ks], acc0);
      acc1 = MFMA32(av, bf1[ks], acc1);
      acc2 = MFMA32(av, bf2[ks], acc2);
    }
    __syncthreads();
    bufp ^= 1;
  }

  // epilogue
  if (ob < 3) {
    const float* s1 = wsf + O_BN1S;
    const float* b1 = wsf + O_BN1B;
#pragma unroll
    for (int nt = 0; nt < 3; ++nt) {
      int o = ob * 96 + (nt << 5) + (l & 31);
      float sc = s1[o], bi = b1[o];
      f32x16 a = (nt == 0) ? acc0 : ((nt == 1) ? acc1 : acc2);
#pragma unroll
      for (int reg = 0; reg < 16; ++reg) {
        int rowD = (reg & 3) + ((reg >> 2) << 3) + ((l >> 5) << 2);
        int pos = p0 + (wid << 5) + rowD;
        float z = a[reg] * sc + bi;
        float sg = 1.f / (1.f + expf(-z));
        Aact[(size_t)pos * 320 + o] = f2bf(sg);
      }
    }
  } else {
#pragma unroll
    for (int nt = 0; nt < 3; ++nt) {
      int o2 = ob * 96 - 288 + (nt << 5) + (l & 31);
      f32x16 a = (nt == 0) ? acc0 : ((nt == 1) ? acc1 : acc2);
      if (o2 < 544) {
#pragma unroll
        for (int reg = 0; reg < 16; ++reg) {
          int rowD = (reg & 3) + ((reg >> 2) << 3) + ((l >> 5) << 2);
          int pos = p0 + (wid << 5) + rowD;
          partial[(size_t)pos * 544 + o2] = a[reg];
        }
      }
    }
  }
}

// ---------------------------------------------------------------------------
// Act GEMM: M=8192, N=576 (544+32 pad), K=320. + partial, BN2, relu -> NCHW.
__global__ __launch_bounds__(256) void gemm_act(
    const u16* __restrict__ Aact, const u16* __restrict__ Wa,
    const float* __restrict__ partial, const float* __restrict__ wsf,
    float* __restrict__ outp)
{
  __shared__ __align__(16) char lraw[96 * 129 * 4];   // 49536 B
  u16 (*Al)[128 * 64] = (u16 (*)[128 * 64])lraw;      // staging: first 32 KB
  float* T = (float*)lraw;                            // epilogue transpose
  const int t = threadIdx.x;
  const int wid = t >> 6, l = t & 63;
  int bx = blockIdx.x;
  int xcd = bx & 7, idx = bx >> 3;          // idx < 48
  int mt = xcd + ((idx & 7) << 3);
  int ob = idx >> 3;                        // 0..5
  int p0 = mt << 7;

  const u16* abase[4];
  int jsw[4], srow[4];
#pragma unroll
  for (int s = 0; s < 4; ++s) {
    int r = (wid << 5) + (s << 3) + (l >> 3);
    jsw[s] = ((l & 7) ^ (r & 7)) << 3;
    srow[s] = (wid << 5) + (s << 3);
    abase[s] = Aact + (size_t)(p0 + r) * 320 + jsw[s];
  }

  f32x16 acc0 = {}, acc1 = {}, acc2 = {};

  auto stage = [&](int ch, int buf) {
#pragma unroll
    for (int s = 0; s < 4; ++s)
      gll16(abase[s] + (ch << 6), &Al[buf][srow[s] << 6]);
  };

  stage(0, 0);
  __syncthreads();

  int bufp = 0;
  const int rr = (wid << 5) + (l & 31);
  for (int ch = 0; ch < 5; ++ch) {
    const u16* wbase = Wa + (((size_t)(ob * 5 + ch)) * 6144) + (l << 3);
    short8 bf0[4], bf1[4], bf2[4];
#pragma unroll
    for (int ks = 0; ks < 4; ++ks) {
      bf0[ks] = *(const short8*)(wbase + (ks << 9));
      bf1[ks] = *(const short8*)(wbase + ((4 + ks) << 9));
      bf2[ks] = *(const short8*)(wbase + ((8 + ks) << 9));
    }
    if (ch + 1 < 5) stage(ch + 1, bufp ^ 1);
#pragma unroll
    for (int ks = 0; ks < 4; ++ks) {
      int jl = (ks << 1) + (l >> 5);
      short8 av = *(const short8*)&Al[bufp][(rr << 6) + ((jl ^ (rr & 7)) << 3)];
      acc0 = MFMA32(av, bf0[ks], acc0);
      acc1 = MFMA32(av, bf1[ks], acc1);
      acc2 = MFMA32(av, bf2[ks], acc2);
    }
    __syncthreads();
    bufp ^= 1;
  }

  // epilogue: +partial, BN2, relu -> LDS transpose -> coalesced NCHW store
  const float* s2p = wsf + O_BN2S;
  const float* b2p = wsf + O_BN2B;
#pragma unroll
  for (int nt = 0; nt < 3; ++nt) {
    int ol = (nt << 5) + (l & 31);
    int o = ob * 96 + ol;
    float sc = 0.f, bi = 0.f;
    if (o < 544) { sc = s2p[o]; bi = b2p[o]; }
    f32x16 a = (nt == 0) ? acc0 : ((nt == 1) ? acc1 : acc2);
#pragma unroll
    for (int reg = 0; reg < 16; ++reg) {
      int rowD = (reg & 3) + ((reg >> 2) << 3) + ((l >> 5) << 2);
      int pos = p0 + (wid << 5) + rowD;
      float pz = 0.f;
      if (o < 544) pz = partial[(size_t)pos * 544 + o];
      float z = (a[reg] + pz) * sc + bi;
      T[ol * 129 + (wid << 5) + rowD] = fmaxf(z, 0.f);
    }
  }
  __syncthreads();
  for (int s2 = t; s2 < 3072; s2 += 256) {
    int ol = s2 >> 5, c4 = s2 & 31;
    int o = ob * 96 + ol;
    if (o < 544) {
      int pos0 = p0 + (c4 << 2);
      int b_ = pos0 >> 10, hw0 = pos0 & 1023;
      int base = ol * 129 + (c4 << 2);
      float4 v;
      v.x = T[base]; v.y = T[base + 1]; v.z = T[base + 2]; v.w = T[base + 3];
      *(float4*)&outp[(((size_t)(b_ * 544 + o)) << 10) + hw0] = v;
    }
  }
}

// ---------------------------------------------------------------------------
extern "C" void kernel_launch(void* const* d_in, const int* in_sizes, int n_in,
                              void* d_out, int out_size, void* d_ws,
                              size_t ws_size, hipStream_t stream)
{
  const float* x       = (const float*)d_in[0];
  const float* wts     = (const float*)d_in[1];
  const float* gamma   = (const float*)d_in[2];
  const float* conv1_w = (const float*)d_in[3];
  const float* bn1s    = (const float*)d_in[4];
  const float* bn1b    = (const float*)d_in[5];
  const float* bn1m    = (const float*)d_in[6];
  const float* bn1v    = (const float*)d_in[7];
  const float* conv2_w = (const float*)d_in[8];
  const float* bn2s    = (const float*)d_in[9];
  const float* bn2b    = (const float*)d_in[10];
  const float* bn2m    = (const float*)d_in[11];
  const float* bn2v    = (const float*)d_in[12];

  char* wsb = (char*)d_ws;
  float* wsf = (float*)d_ws;
  u16* Gb    = (u16*)(wsb + O_G_B);
  u16* Aact  = (u16*)(wsb + O_AACT_B);
  float* prt = (float*)(wsb + O_PART_B);
  u16* Wf    = (u16*)(wsb + O_WF_B);
  u16* Wa    = (u16*)(wsb + O_WA_B);
  float* out = (float*)d_out;

  prep_kernel<<<1, 256, 0, stream>>>(wts, gamma, bn1s, bn1b, bn1m, bn1v,
                                     bn2s, bn2b, bn2m, bn2v, wsf);
  stats_kernel<<<256, 256, 0, stream>>>(x, wsf, Aact);
  wcvt_kernel<<<2034, 256, 0, stream>>>(conv1_w, conv2_w, Wf, Wa);
  g_kernel<<<2048, 256, 0, stream>>>(x, wsf, Gb);
  gemm_fused<<<576, 256, 0, stream>>>(Gb, Wf, wsf, Aact, prt);
  gemm_act<<<384, 256, 0, stream>>>(Aact, Wa, prt, wsf, out);
}